// Round 5
// baseline (213.565 us; speedup 1.0000x reference)
//
#include <hip/hip_runtime.h>
#include <hip/hip_bf16.h>

// Problem constants
#define NN    8
#define CC    32
#define HH    48
#define WW    48
#define OCC   32
#define HID   256
#define FEAT  288          // C*K*K
#define RTOT  9216         // (H*S)*(W*S)
#define COLS  9216         // FEAT*OC
#define XUP   96
#define YUP   96
#define OUTSZ (NN*OCC*XUP*YUP)   // 2,359,296 floats

using bf16x8 = __attribute__((ext_vector_type(8))) __bf16;
using bf16x4 = __attribute__((ext_vector_type(4))) __bf16;
using f32x4  = __attribute__((ext_vector_type(4))) float;
using f32x2  = __attribute__((ext_vector_type(2))) float;

#define GLOAD_LDS16(gp, lp)                                                        \
  __builtin_amdgcn_global_load_lds((const __attribute__((address_space(1))) void*)(gp), \
                                   (__attribute__((address_space(3))) void*)(lp), 16, 0, 0)

// ---------------------------------------------------------------------------
// Kernel 1: hmid = relu(v @ w1 + b1), bf16, MFMA A-fragment order (verified):
//   frag = (r/16)*8 + k/32 ; lane = ((k/8)%4)*16 + r%16 ; elem = k%8
// ---------------------------------------------------------------------------
__global__ void prep_hmid(const float* __restrict__ v, const float* __restrict__ w1,
                          const float* __restrict__ b1, __hip_bfloat16* __restrict__ hmidp) {
  int r = blockIdx.x;      // 0..9215
  int t = threadIdx.x;     // 0..255 = hidden index k
  float v0 = v[r*3+0], v1 = v[r*3+1], v2 = v[r*3+2];
  float val = v0*w1[t] + v1*w1[HID+t] + v2*w1[2*HID+t] + b1[t];
  val = fmaxf(val, 0.0f);
  int dst = ((r>>4)*8 + (t>>5))*512 + ((t>>3)&3)*128 + (r&15)*8 + (t&7);
  hmidp[dst] = __float2bfloat16(val);
}

// ---------------------------------------------------------------------------
// Kernel 2: w2 -> bf16, B-fragment order; slice (colchunk,kb) = 8192B contiguous.
// ---------------------------------------------------------------------------
__global__ void prep_w2(const float* __restrict__ w2, __hip_bfloat16* __restrict__ w2p) {
  int idx = blockIdx.x*256 + threadIdx.x;   // 0 .. 256*9216-1
  int k   = idx / COLS;
  int col = idx % COLS;
  float val = w2[idx];                      // w2[k][col], row-major
  int colchunk = col >> 7;
  int cg   = (col >> 4) & 7;
  int lane = (((k>>3)&3)<<4) | (col & 15);
  int kb   = k >> 5;
  int i    = k & 7;
  int dst  = (((colchunk*8 + kb)*8 + cg)*64 + lane)*8 + i;
  w2p[dst] = __float2bfloat16(val);
}

// ---------------------------------------------------------------------------
// Kernel 3: fused GEMM + apply. Counted-vmcnt pipeline, 2 barriers/chunk,
// 2-deep register prefetch of B fragments (ds_read latency hidden under MFMA).
// Ring-overwrite hazard: stage(u+5) overwrites ring[(u+1)&3]; guarded by
// lgkmcnt(2) after issuing reads of u+2 (only 4 ds_reads live in this phase).
// ---------------------------------------------------------------------------
__launch_bounds__(256, 2)
__global__ void fused_main(const float* __restrict__ F_LR,
                           const __hip_bfloat16* __restrict__ hmidp,
                           const __hip_bfloat16* __restrict__ w2p,
                           const float* __restrict__ b2,
                           float* __restrict__ outp,
                           int G, int nch) {
  __shared__ __align__(16) __bf16 pat[CC][3][18][NN];   // 27648B [c][ki][wi][n]
  __shared__ __align__(16) float  wc[4*OCC*32];         // 16384B [f][oc][r^swz]
  __shared__ __align__(16) __bf16 Bring[4*4096];        // 32768B ring of 4 slices
  __shared__ __align__(16) float  biasb[256];           //  1024B (2 chunks)
  __shared__ __align__(16) char   dummy[2048];          //  dead sink for tail stages

  const int tid  = threadIdx.x;
  const int lane = tid & 63;
  const int wv   = tid >> 6;
  const int blk  = blockIdx.x;
  const int rowtile = blk / G;            // 0..287
  const int g       = blk - rowtile*G;    // g parity == XCD parity (L2 pinning)
  const int X  = rowtile / 3;
  const int Yh = rowtile - X*3;
  const int h  = X >> 1;
  const int w0 = Yh * 16;
  const int l15 = lane & 15;
  const int qt  = lane >> 4;
  const int oc  = lane & 31;
  const int nh  = lane >> 5;
  const int colchunk0 = g*nch;
  const int NT = nch*8;

  // ---- B stage: wave wv stages its own 2KB quarter of slice t ----
  const char* w2base = (const char*)w2p + (size_t)colchunk0*65536;
  char* BringB = (char*)Bring;
  auto stage_any = [&](int t) {
    if (t < NT) {
      const char* src = w2base + (size_t)t*8192 + wv*2048 + lane*16;
      char* dst = BringB + (t&3)*8192 + wv*2048;
      GLOAD_LDS16(src, dst);
      GLOAD_LDS16(src + 1024, dst + 1024);
    } else {   // dummy: keep FIFO depth invariant; nobody reads `dummy`
      const char* src = w2base + wv*2048 + lane*16;
      GLOAD_LDS16(src, (char*)dummy);
      GLOAD_LDS16(src + 1024, (char*)dummy + 1024);
    }
  };
  stage_any(0); stage_any(1); stage_any(2);
  asm volatile("" ::: "memory");   // pin: stages are the oldest vmem ops

  // ---- A fragments -> registers (16 coalesced b128 loads) ----
  bf16x8 a[2][8];
  {
    const bf16x8* ap = reinterpret_cast<const bf16x8*>(hmidp) + (size_t)rowtile*1024 + lane;
    #pragma unroll
    for (int mg = 0; mg < 2; ++mg)
      #pragma unroll
      for (int kb = 0; kb < 8; ++kb) a[mg][kb] = ap[(mg*8 + kb)*64];
  }

  // ---- stage patches (coalesced: consecutive lanes -> consecutive ww) ----
  for (int idx = tid; idx < NN*CC*3*18; idx += 256) {
    int wi = idx % 18;
    int t2 = idx / 18;
    int ki = t2 % 3;
    int t3 = t2 / 3;
    int c  = t3 & 31;
    int n  = t3 >> 5;
    int hh = h - 1 + ki;
    int ww = w0 - 1 + wi;
    float val = 0.f;
    if ((unsigned)hh < (unsigned)HH && (unsigned)ww < (unsigned)WW)
      val = F_LR[((n*CC + c)*HH + hh)*WW + ww];
    pat[c][ki][wi][n] = (__bf16)val;
  }
  asm volatile("s_waitcnt lgkmcnt(0)" ::: "memory");
  __builtin_amdgcn_sched_barrier(0);
  __builtin_amdgcn_s_barrier();

  f32x2 oacc2[8][2];                      // [row][q-pair]
  #pragma unroll
  for (int i = 0; i < 8; ++i) { oacc2[i][0] = 0.f; oacc2[i][1] = 0.f; }

  auto ldb = [&](int u, int off) -> bf16x8 {
    return *(const bf16x8*)(BringB + (size_t)(u&3)*8192 + wv*2048 + off + lane*16);
  };

  for (int ch = 0; ch < nch; ++ch) {
    const int t0 = ch*8;
    if ((ch & 1) == 0) {   // bias for (ch, ch+1): 1024B (uniform across waves)
      const char* bsrc = (const char*)(b2 + (size_t)(colchunk0 + ch)*128) + lane*16;
      GLOAD_LDS16(bsrc, (char*)biasb);
    }

    f32x4 acc00 = {0,0,0,0}, acc01 = {0,0,0,0}, acc10 = {0,0,0,0}, acc11 = {0,0,0,0};

    // ---- preamble: fill both register sets (slices t0, t0+1) ----
    asm volatile("s_waitcnt vmcnt(4)" ::: "memory");     // t0 landed
    bf16x8 b0A = ldb(t0, 0),   b1A = ldb(t0, 1024);
    stage_any(t0 + 3);
    asm volatile("s_waitcnt vmcnt(4)" ::: "memory");     // t0+1 landed
    bf16x8 b0B = ldb(t0+1, 0), b1B = ldb(t0+1, 1024);
    asm volatile("s_waitcnt lgkmcnt(2)" ::: "memory");   // A-set reads retired
    stage_any(t0 + 4);                                   // overwrites ring[t0&3]

    #pragma unroll
    for (int s = 0; s < 8; ++s) {
      const bf16x8 cb0 = (s & 1) ? b0B : b0A;
      const bf16x8 cb1 = (s & 1) ? b1B : b1A;
      __builtin_amdgcn_s_setprio(1);
      acc00 = __builtin_amdgcn_mfma_f32_16x16x32_bf16(a[0][s], cb0, acc00, 0,0,0);
      acc01 = __builtin_amdgcn_mfma_f32_16x16x32_bf16(a[0][s], cb1, acc01, 0,0,0);
      acc10 = __builtin_amdgcn_mfma_f32_16x16x32_bf16(a[1][s], cb0, acc10, 0,0,0);
      acc11 = __builtin_amdgcn_mfma_f32_16x16x32_bf16(a[1][s], cb1, acc11, 0,0,0);
      __builtin_amdgcn_s_setprio(0);
      if (s < 6) {
        asm volatile("s_waitcnt vmcnt(4)" ::: "memory"); // t0+s+2 landed
        if (s & 1) { b0B = ldb(t0+s+2, 0); b1B = ldb(t0+s+2, 1024); }
        else       { b0A = ldb(t0+s+2, 0); b1A = ldb(t0+s+2, 1024); }
        asm volatile("s_waitcnt lgkmcnt(2)" ::: "memory"); // reads of t0+s+1 retired
        stage_any(t0 + s + 5);                           // overwrites ring[(t0+s+1)&3]
      }
    }

    // ---- wc write: wc[wv][oc][r^swz] = acc + bias ----
    asm volatile("s_waitcnt vmcnt(6)" ::: "memory");     // bias (older) complete
    {
      float bias0 = biasb[(ch&1)*128 + wv*32 + l15];
      float bias1 = biasb[(ch&1)*128 + wv*32 + 16 + l15];
      #pragma unroll
      for (int mg = 0; mg < 2; ++mg) {
        #pragma unroll
        for (int ng = 0; ng < 2; ++ng) {
          f32x4 A = (mg==0) ? (ng==0?acc00:acc01) : (ng==0?acc10:acc11);
          float bb = ng ? bias1 : bias0;
          A[0]+=bb; A[1]+=bb; A[2]+=bb; A[3]+=bb;
          int ocx  = ng*16 + l15;
          int ridx = (mg*16 + qt*4) ^ ((ocx&7)<<2);
          *(f32x4*)&wc[wv*1024 + ocx*32 + ridx] = A;
        }
      }
    }
    asm volatile("s_waitcnt lgkmcnt(0)" ::: "memory");
    __builtin_amdgcn_sched_barrier(0);
    __builtin_amdgcn_s_barrier();                        // wc visible (vmcnt NOT drained)

    // ---- apply (packed f32x2 math) ----
    const int swz = (oc & 7) << 2;
    #pragma unroll
    for (int fl = 0; fl < 4; ++fl) {
      const int f   = (colchunk0 + ch)*4 + fl;
      const int c   = f / 9;
      const int rem = f - c*9;
      const int ki  = rem / 3;
      const int kj  = rem - ki*3;
      const f32x4 wlo = *(const f32x4*)&wc[fl*1024 + oc*32 + ((wv*8    ) ^ swz)];
      const f32x4 whi = *(const f32x4*)&wc[fl*1024 + oc*32 + ((wv*8 + 4) ^ swz)];
      const __bf16* pbase = &pat[c][ki][0][0] + nh*4;
      #pragma unroll
      for (int rrh = 0; rrh < 4; ++rrh) {
        bf16x4 pq = *(const bf16x4*)(pbase + (wv*4 + rrh + kj)*8);
        f32x2 p01; p01[0] = (float)pq[0]; p01[1] = (float)pq[1];
        f32x2 p23; p23[0] = (float)pq[2]; p23[1] = (float)pq[3];
        float w0v = (rrh < 2) ? ((rrh == 0) ? wlo[0] : wlo[2]) : ((rrh == 2) ? whi[0] : whi[2]);
        float w1v = (rrh < 2) ? ((rrh == 0) ? wlo[1] : wlo[3]) : ((rrh == 2) ? whi[1] : whi[3]);
        oacc2[rrh*2][0]   += p01 * w0v;
        oacc2[rrh*2][1]   += p23 * w0v;
        oacc2[rrh*2+1][0] += p01 * w1v;
        oacc2[rrh*2+1][1] += p23 * w1v;
      }
    }
    asm volatile("s_waitcnt lgkmcnt(0)" ::: "memory");
    __builtin_amdgcn_sched_barrier(0);
    __builtin_amdgcn_s_barrier();                        // apply done; wc reusable
  }

  // ---- epilogue: out[n, oc, X, Yh*32 + wv*8 .. +7] ----
  float* OP = outp + (size_t)g*OUTSZ;
  #pragma unroll
  for (int q = 0; q < 4; ++q) {
    int n = nh*4 + q;
    f32x4 v0, v1;
    v0[0]=oacc2[0][q>>1][q&1]; v0[1]=oacc2[1][q>>1][q&1];
    v0[2]=oacc2[2][q>>1][q&1]; v0[3]=oacc2[3][q>>1][q&1];
    v1[0]=oacc2[4][q>>1][q&1]; v1[1]=oacc2[5][q>>1][q&1];
    v1[2]=oacc2[6][q>>1][q&1]; v1[3]=oacc2[7][q>>1][q&1];
    float* dst = OP + (((size_t)(n*OCC + oc)*XUP + X)*YUP + Yh*32 + wv*8);
    *(f32x4*)dst     = v0;
    *(f32x4*)(dst+4) = v1;
  }
}

// ---------------------------------------------------------------------------
// Kernel 4 (G=2 only): out = P0 + P1 (deterministic)
// ---------------------------------------------------------------------------
__global__ void reduce2(const float* __restrict__ P, float* __restrict__ out) {
  int i = blockIdx.x*256 + threadIdx.x;
  if (i < OUTSZ/4) {
    f32x4 a = ((const f32x4*)P)[i];
    f32x4 b = ((const f32x4*)(P + OUTSZ))[i];
    ((f32x4*)out)[i] = a + b;
  }
}

// ---------------------------------------------------------------------------
extern "C" void kernel_launch(void* const* d_in, const int* in_sizes, int n_in,
                              void* d_out, int out_size, void* d_ws, size_t ws_size,
                              hipStream_t stream) {
  const float* F_LR = (const float*)d_in[0];
  const float* v    = (const float*)d_in[1];
  const float* w1   = (const float*)d_in[2];
  const float* b1   = (const float*)d_in[3];
  const float* w2   = (const float*)d_in[4];
  const float* b2   = (const float*)d_in[5];
  float* out = (float*)d_out;

  const size_t prepBytes = (size_t)RTOT*HID*2;          // 4,718,592 each
  const size_t need2 = 2*prepBytes + 2ull*OUTSZ*4;      // 28,311,552
  const int G   = (ws_size >= need2) ? 2 : 1;
  const int nch = 72 / G;

  __hip_bfloat16* hmidp = (__hip_bfloat16*)d_ws;
  __hip_bfloat16* w2p   = (__hip_bfloat16*)((char*)d_ws + prepBytes);
  float* P = (float*)((char*)d_ws + 2*prepBytes);
  float* target = (G == 2) ? P : out;

  hipLaunchKernelGGL(prep_hmid, dim3(RTOT), dim3(HID), 0, stream, v, w1, b1, hmidp);
  hipLaunchKernelGGL(prep_w2,   dim3((HID*COLS)/256), dim3(256), 0, stream, w2, w2p);
  hipLaunchKernelGGL(fused_main, dim3(288*G), dim3(256), 0, stream,
                     F_LR, hmidp, w2p, b2, target, G, nch);
  if (G == 2)
    hipLaunchKernelGGL(reduce2, dim3(OUTSZ/4/256), dim3(256), 0, stream, P, out);
}

// Round 10
// 199.099 us; speedup vs baseline: 1.0727x; 1.0727x over previous
//
#include <hip/hip_runtime.h>
#include <hip/hip_bf16.h>

// Problem constants
#define NN    8
#define CC    32
#define HH    48
#define WW    48
#define OCC   32
#define HID   256
#define FEAT  288          // C*K*K
#define RTOT  9216         // (H*S)*(W*S)
#define COLS  9216         // FEAT*OC
#define XUP   96
#define YUP   96
#define OUTSZ (NN*OCC*XUP*YUP)   // 2,359,296 floats

using bf16x8 = __attribute__((ext_vector_type(8))) __bf16;
using bf16x4 = __attribute__((ext_vector_type(4))) __bf16;
using f32x4  = __attribute__((ext_vector_type(4))) float;

#define GLOAD_LDS16(gp, lp)                                                        \
  __builtin_amdgcn_global_load_lds((const __attribute__((address_space(1))) void*)(gp), \
                                   (__attribute__((address_space(3))) void*)(lp), 16, 0, 0)

// ---------------------------------------------------------------------------
// Kernel 1: hmid = relu(v @ w1 + b1), bf16, MFMA A-fragment order (verified):
//   frag = (r/16)*8 + k/32 ; lane = ((k/8)%4)*16 + r%16 ; elem = k%8
// ---------------------------------------------------------------------------
__global__ void prep_hmid(const float* __restrict__ v, const float* __restrict__ w1,
                          const float* __restrict__ b1, __hip_bfloat16* __restrict__ hmidp) {
  int r = blockIdx.x;      // 0..9215
  int t = threadIdx.x;     // 0..255 = hidden index k
  float v0 = v[r*3+0], v1 = v[r*3+1], v2 = v[r*3+2];
  float val = v0*w1[t] + v1*w1[HID+t] + v2*w1[2*HID+t] + b1[t];
  val = fmaxf(val, 0.0f);
  int dst = ((r>>4)*8 + (t>>5))*512 + ((t>>3)&3)*128 + (r&15)*8 + (t&7);
  hmidp[dst] = __float2bfloat16(val);
}

// ---------------------------------------------------------------------------
// Kernel 2: w2 -> bf16, B-fragment order grouped into 8KB slices:
//   colchunk = col/128 (72), kb = k/32 (8), cg = (col%128)/16 (8),
//   lane = ((k/8)%4)*16 + col%16, elem = k%8
//   slice (colchunk,kb) is 8192B contiguous -> global_load_lds-able linearly.
// ---------------------------------------------------------------------------
__global__ void prep_w2(const float* __restrict__ w2, __hip_bfloat16* __restrict__ w2p) {
  int idx = blockIdx.x*256 + threadIdx.x;   // 0 .. 256*9216-1
  int k   = idx / COLS;
  int col = idx % COLS;
  float val = w2[idx];                      // w2[k][col], row-major
  int colchunk = col >> 7;
  int cg   = (col >> 4) & 7;
  int lane = (((k>>3)&3)<<4) | (col & 15);
  int kb   = k >> 5;
  int i    = k & 7;
  int dst  = (((colchunk*8 + kb)*8 + cg)*64 + lane)*8 + i;
  w2p[dst] = __float2bfloat16(val);
}

// ---------------------------------------------------------------------------
// Kernel 3: fused GEMM + apply. Counted-vmcnt pipeline, 2 barriers/chunk.
// Block = 32 rows (one X, 32 Y) x col-group g; 256 thr = 4 waves.
// Each wave stages AND consumes its own B quarter -> no barriers for B.
// TAIL: dummy stages keep exactly 3 slices (6 loads) in the vmem FIFO at
// every vmcnt(4), so the wait always drains through slice t.
// R10 CHANGE (only one): XCD-chunked blk->(rowtile,g) decode when G==2:
//   xcd = blk&7; g = xcd&1; rowtile = (xcd>>1)*72 + blk>>3
// Each XCD then streams ONE 2.36MB w2p half (L2-resident) and a contiguous
// 72-rowtile run. Bijective; zero data-path mapping changes.
// ---------------------------------------------------------------------------
__launch_bounds__(256, 2)
__global__ void fused_main(const float* __restrict__ F_LR,
                           const __hip_bfloat16* __restrict__ hmidp,
                           const __hip_bfloat16* __restrict__ w2p,
                           const float* __restrict__ b2,
                           float* __restrict__ outp,
                           int G, int nch) {
  __shared__ __align__(16) __bf16 pat[CC][3][18][NN];   // 27648B [c][ki][wi][n]
  __shared__ __align__(16) float  wc[4*OCC*32];         // 16384B [f][oc][r^swz]
  __shared__ __align__(16) __bf16 Bring[4*4096];        // 32768B ring of 4 slices
  __shared__ __align__(16) float  biasb[256];           //  1024B (2 chunks)
  __shared__ __align__(16) char   dummy[2048];          //  dead sink for tail stages

  const int tid  = threadIdx.x;
  const int lane = tid & 63;
  const int wv   = tid >> 6;
  const int blk  = blockIdx.x;
  int rowtile, g;
  if (G == 2) {            // XCD-chunked decode (grid = 576, 72 blocks per XCD)
    int xcd = blk & 7;
    int j   = blk >> 3;    // 0..71
    g       = xcd & 1;
    rowtile = (xcd >> 1)*72 + j;
  } else {
    rowtile = blk;
    g       = 0;
  }
  const int X  = rowtile / 3;
  const int Yh = rowtile - X*3;
  const int h  = X >> 1;
  const int w0 = Yh * 16;
  const int l15 = lane & 15;
  const int qt  = lane >> 4;
  const int oc  = lane & 31;
  const int nh  = lane >> 5;
  const int NT = nch*8;

  // ---- B stage: wave wv stages its own 2KB quarter of slice t ----
  const char* w2base = (const char*)w2p + (size_t)g*nch*65536;
  char* BringB = (char*)Bring;
  auto stage_any = [&](int t) {
    if (t < NT) {
      const char* src = w2base + (size_t)t*8192 + wv*2048 + lane*16;
      char* dst = BringB + (t&3)*8192 + wv*2048;
      GLOAD_LDS16(src, dst);
      GLOAD_LDS16(src + 1024, dst + 1024);
    } else {   // dummy: keep FIFO depth invariant; nobody reads `dummy`
      const char* src = w2base + wv*2048 + lane*16;
      GLOAD_LDS16(src, (char*)dummy);
      GLOAD_LDS16(src + 1024, (char*)dummy + 1024);
    }
  };
  stage_any(0); stage_any(1); stage_any(2);
  asm volatile("" ::: "memory");   // pin: stages are the 6 oldest vmem ops

  // ---- A fragments -> registers (16 coalesced b128 loads) ----
  bf16x8 a[2][8];
  {
    const bf16x8* ap = reinterpret_cast<const bf16x8*>(hmidp) + (size_t)rowtile*1024 + lane;
    #pragma unroll
    for (int mg = 0; mg < 2; ++mg)
      #pragma unroll
      for (int kb = 0; kb < 8; ++kb) a[mg][kb] = ap[(mg*8 + kb)*64];
  }

  // ---- stage patches: pat[c][ki][wi][n]; thread = (n,c) ----
  {
    const int n = tid >> 5, c = tid & 31;
    const float* fsrc = F_LR + ((size_t)(n*CC + c)*HH)*WW;
    #pragma unroll
    for (int ki = 0; ki < 3; ++ki) {
      int hh = h - 1 + ki;
      bool hok = (unsigned)hh < (unsigned)HH;
      #pragma unroll
      for (int wi = 0; wi < 18; ++wi) {
        int ww = w0 - 1 + wi;
        float val = (hok && (unsigned)ww < (unsigned)WW) ? fsrc[hh*WW + ww] : 0.f;
        pat[c][ki][wi][n] = (__bf16)val;
      }
    }
  }
  asm volatile("s_waitcnt lgkmcnt(0)" ::: "memory");
  __builtin_amdgcn_sched_barrier(0);
  __builtin_amdgcn_s_barrier();

  float oacc[8][4];
  #pragma unroll
  for (int i = 0; i < 8; ++i)
    { oacc[i][0]=0.f; oacc[i][1]=0.f; oacc[i][2]=0.f; oacc[i][3]=0.f; }

  for (int ch = 0; ch < nch; ++ch) {
    if ((ch & 1) == 0) {   // bias for (ch, ch+1): 1024B, all waves redundantly (same data)
      const char* bsrc = (const char*)(b2 + (size_t)(g*nch + ch)*128) + lane*16;
      GLOAD_LDS16(bsrc, (char*)biasb);
    }

    f32x4 acc00 = {0,0,0,0}, acc01 = {0,0,0,0}, acc10 = {0,0,0,0}, acc11 = {0,0,0,0};

    #pragma unroll
    for (int s = 0; s < 8; ++s) {
      const int t = ch*8 + s;
      asm volatile("s_waitcnt vmcnt(4)" ::: "memory");   // slice t landed (t+1,t+2 in flight)
      const char* bufp = BringB + (size_t)(t&3)*8192 + wv*2048;
      bf16x8 b0 = *(const bf16x8*)(bufp + lane*16);
      bf16x8 b1 = *(const bf16x8*)(bufp + 1024 + lane*16);
      stage_any(t + 3);
      acc00 = __builtin_amdgcn_mfma_f32_16x16x32_bf16(a[0][s], b0, acc00, 0,0,0);
      acc01 = __builtin_amdgcn_mfma_f32_16x16x32_bf16(a[0][s], b1, acc01, 0,0,0);
      acc10 = __builtin_amdgcn_mfma_f32_16x16x32_bf16(a[1][s], b0, acc10, 0,0,0);
      acc11 = __builtin_amdgcn_mfma_f32_16x16x32_bf16(a[1][s], b1, acc11, 0,0,0);
    }

    // ---- wc write: wc[wv][oc][r^swz] = acc + bias ----
    asm volatile("s_waitcnt vmcnt(6)" ::: "memory");     // bias GLOAD (older) complete
    {
      float bias0 = biasb[(ch&1)*128 + wv*32 + l15];
      float bias1 = biasb[(ch&1)*128 + wv*32 + 16 + l15];
      #pragma unroll
      for (int mg = 0; mg < 2; ++mg) {
        #pragma unroll
        for (int ng = 0; ng < 2; ++ng) {
          f32x4 A = (mg==0) ? (ng==0?acc00:acc01) : (ng==0?acc10:acc11);
          float bb = ng ? bias1 : bias0;
          A[0]+=bb; A[1]+=bb; A[2]+=bb; A[3]+=bb;
          int ocx  = ng*16 + l15;
          int ridx = (mg*16 + qt*4) ^ ((ocx&7)<<2);
          *(f32x4*)&wc[wv*1024 + ocx*32 + ridx] = A;
        }
      }
    }
    asm volatile("s_waitcnt lgkmcnt(0)" ::: "memory");
    __builtin_amdgcn_sched_barrier(0);
    __builtin_amdgcn_s_barrier();                        // wc visible (vmcnt NOT drained)

    // ---- apply ----
    const int swz = (oc & 7) << 2;
    #pragma unroll
    for (int fl = 0; fl < 4; ++fl) {
      const int f   = (g*nch + ch)*4 + fl;
      const int c   = f / 9;
      const int rem = f - c*9;
      const int ki  = rem / 3;
      const int kj  = rem - ki*3;
      const f32x4 wlo = *(const f32x4*)&wc[fl*1024 + oc*32 + ((wv*8    ) ^ swz)];
      const f32x4 whi = *(const f32x4*)&wc[fl*1024 + oc*32 + ((wv*8 + 4) ^ swz)];
      const __bf16* pbase = &pat[c][ki][0][0] + nh*4;
      #pragma unroll
      for (int rrh = 0; rrh < 4; ++rrh) {
        bf16x4 pq = *(const bf16x4*)(pbase + (wv*4 + rrh + kj)*8);
        float w0v = (rrh < 2) ? ((rrh == 0) ? wlo[0] : wlo[2]) : ((rrh == 2) ? whi[0] : whi[2]);
        float w1v = (rrh < 2) ? ((rrh == 0) ? wlo[1] : wlo[3]) : ((rrh == 2) ? whi[1] : whi[3]);
        #pragma unroll
        for (int q = 0; q < 4; ++q) {
          float pv = (float)pq[q];
          oacc[rrh*2][q]   += w0v * pv;
          oacc[rrh*2+1][q] += w1v * pv;
        }
      }
    }
    asm volatile("s_waitcnt lgkmcnt(0)" ::: "memory");
    __builtin_amdgcn_sched_barrier(0);
    __builtin_amdgcn_s_barrier();                        // apply done; wc reusable
  }

  // ---- epilogue: out[n, oc, X, Yh*32 + wv*8 .. +7] ----
  float* OP = outp + (size_t)g*OUTSZ;
  #pragma unroll
  for (int q = 0; q < 4; ++q) {
    int n = nh*4 + q;
    f32x4 v0, v1;
    v0[0]=oacc[0][q]; v0[1]=oacc[1][q]; v0[2]=oacc[2][q]; v0[3]=oacc[3][q];
    v1[0]=oacc[4][q]; v1[1]=oacc[5][q]; v1[2]=oacc[6][q]; v1[3]=oacc[7][q];
    float* dst = OP + (((size_t)(n*OCC + oc)*XUP + X)*YUP + Yh*32 + wv*8);
    *(f32x4*)dst     = v0;
    *(f32x4*)(dst+4) = v1;
  }
}

// ---------------------------------------------------------------------------
// Kernel 4 (G=2 only): out = P0 + P1 (deterministic)
// ---------------------------------------------------------------------------
__global__ void reduce2(const float* __restrict__ P, float* __restrict__ out) {
  int i = blockIdx.x*256 + threadIdx.x;
  if (i < OUTSZ/4) {
    f32x4 a = ((const f32x4*)P)[i];
    f32x4 b = ((const f32x4*)(P + OUTSZ))[i];
    ((f32x4*)out)[i] = a + b;
  }
}

// ---------------------------------------------------------------------------
extern "C" void kernel_launch(void* const* d_in, const int* in_sizes, int n_in,
                              void* d_out, int out_size, void* d_ws, size_t ws_size,
                              hipStream_t stream) {
  const float* F_LR = (const float*)d_in[0];
  const float* v    = (const float*)d_in[1];
  const float* w1   = (const float*)d_in[2];
  const float* b1   = (const float*)d_in[3];
  const float* w2   = (const float*)d_in[4];
  const float* b2   = (const float*)d_in[5];
  float* out = (float*)d_out;

  const size_t prepBytes = (size_t)RTOT*HID*2;          // 4,718,592 each
  const size_t need2 = 2*prepBytes + 2ull*OUTSZ*4;      // 28,311,552
  const int G   = (ws_size >= need2) ? 2 : 1;
  const int nch = 72 / G;

  __hip_bfloat16* hmidp = (__hip_bfloat16*)d_ws;
  __hip_bfloat16* w2p   = (__hip_bfloat16*)((char*)d_ws + prepBytes);
  float* P = (float*)((char*)d_ws + 2*prepBytes);
  float* target = (G == 2) ? P : out;

  hipLaunchKernelGGL(prep_hmid, dim3(RTOT), dim3(HID), 0, stream, v, w1, b1, hmidp);
  hipLaunchKernelGGL(prep_w2,   dim3((HID*COLS)/256), dim3(256), 0, stream, w2, w2p);
  hipLaunchKernelGGL(fused_main, dim3(288*G), dim3(256), 0, stream,
                     F_LR, hmidp, w2p, b2, target, G, nch);
  if (G == 2)
    hipLaunchKernelGGL(reduce2, dim3(OUTSZ/4/256), dim3(256), 0, stream, P, out);
}

// Round 11
// 176.140 us; speedup vs baseline: 1.2125x; 1.1303x over previous
//
#include <hip/hip_runtime.h>
#include <hip/hip_bf16.h>

// Problem constants
#define NN    8
#define CC    32
#define HH    48
#define WW    48
#define OCC   32
#define HID   256
#define FEAT  288          // C*K*K
#define RTOT  9216         // (H*S)*(W*S)
#define COLS  9216         // FEAT*OC
#define XUP   96
#define YUP   96
#define OUTSZ (NN*OCC*XUP*YUP)   // 2,359,296 floats

using bf16x8 = __attribute__((ext_vector_type(8))) __bf16;
using bf16x4 = __attribute__((ext_vector_type(4))) __bf16;
using f32x4  = __attribute__((ext_vector_type(4))) float;

// ---------------------------------------------------------------------------
// Kernel 1: hmid = relu(v @ w1 + b1), bf16, MFMA A-fragment order (verified):
//   frag = (r/16)*8 + k/32 ; lane = ((k/8)%4)*16 + r%16 ; elem = k%8
// ---------------------------------------------------------------------------
__global__ void prep_hmid(const float* __restrict__ v, const float* __restrict__ w1,
                          const float* __restrict__ b1, __hip_bfloat16* __restrict__ hmidp) {
  int r = blockIdx.x;      // 0..9215
  int t = threadIdx.x;     // 0..255 = hidden index k
  float v0 = v[r*3+0], v1 = v[r*3+1], v2 = v[r*3+2];
  float val = v0*w1[t] + v1*w1[HID+t] + v2*w1[2*HID+t] + b1[t];
  val = fmaxf(val, 0.0f);
  int dst = ((r>>4)*8 + (t>>5))*512 + ((t>>3)&3)*128 + (r&15)*8 + (t&7);
  hmidp[dst] = __float2bfloat16(val);
}

// ---------------------------------------------------------------------------
// Kernel 2: w2 -> bf16, B-fragment order grouped into 8KB slices (verified):
//   colchunk = col/128 (72), kb = k/32 (8), cg = (col%128)/16 (8),
//   lane = ((k/8)%4)*16 + col%16, elem = k%8
// ---------------------------------------------------------------------------
__global__ void prep_w2(const float* __restrict__ w2, __hip_bfloat16* __restrict__ w2p) {
  int idx = blockIdx.x*256 + threadIdx.x;   // 0 .. 256*9216-1
  int k   = idx / COLS;
  int col = idx % COLS;
  float val = w2[idx];                      // w2[k][col], row-major
  int colchunk = col >> 7;
  int cg   = (col >> 4) & 7;
  int lane = (((k>>3)&3)<<4) | (col & 15);
  int kb   = k >> 5;
  int i    = k & 7;
  int dst  = (((colchunk*8 + kb)*8 + cg)*64 + lane)*8 + i;
  w2p[dst] = __float2bfloat16(val);
}

// ---------------------------------------------------------------------------
// Kernel 3: fused GEMM + apply.
// R11 CHANGE: B fragments load DIRECTLY global->VGPR (same bytes the LDS
// staging delivered - staging was address-preserving). Double-buffered
// half-chunks (4 slices = 8 b128 loads per set); consume A -> refill A ->
// consume B -> refill B. NO manual vmcnt: compiler inserts waits for plain
// loads. Bias via one-time LDS table. Only asm left: R10-proven lgkm-only
// barrier triple (keeps vmem in flight across barriers).
// LDS (dynamic): pat 27648 + wc 16384 + biasL nch*256 = 53,248 (G=2).
// ---------------------------------------------------------------------------
#define BARRIER_LGKM() do {                              \
    asm volatile("s_waitcnt lgkmcnt(0)" ::: "memory");   \
    __builtin_amdgcn_sched_barrier(0);                   \
    __builtin_amdgcn_s_barrier();                        \
  } while (0)

#define ISSUE_HALF(SET, CH, H) do {                                              \
    const char* _b = w2base + ((size_t)((CH)*8 + (H)*4))*8192 + wv*2048          \
                     + (size_t)lane*16;                                          \
    _Pragma("unroll")                                                            \
    for (int _i = 0; _i < 4; ++_i) {                                             \
      SET[0][_i] = *(const bf16x8*)(_b + _i*8192);                               \
      SET[1][_i] = *(const bf16x8*)(_b + _i*8192 + 1024);                        \
    }                                                                            \
  } while (0)

__launch_bounds__(256, 2)
__global__ void fused_main(const float* __restrict__ F_LR,
                           const __hip_bfloat16* __restrict__ hmidp,
                           const __hip_bfloat16* __restrict__ w2p,
                           const float* __restrict__ b2,
                           float* __restrict__ outp,
                           int G, int nch) {
  extern __shared__ __align__(16) char smem[];
  __bf16* patB  = (__bf16*)smem;                 // 27648B: pat[c][ki][wi(18)][n(8)]
  float*  wc    = (float*)(smem + 27648);        // 16384B: [fl][oc][r^swz]
  __bf16* biasL = (__bf16*)(smem + 44032);       // nch*128 bf16

  const int tid  = threadIdx.x;
  const int lane = tid & 63;
  const int wv   = tid >> 6;
  const int blk  = blockIdx.x;
  int rowtile, g;
  if (G == 2) {            // XCD-chunked decode (grid = 576, 72 blocks per XCD)
    int xcd = blk & 7;
    int j   = blk >> 3;    // 0..71
    g       = xcd & 1;
    rowtile = (xcd >> 1)*72 + j;
  } else {
    rowtile = blk;
    g       = 0;
  }
  const int X  = rowtile / 3;
  const int Yh = rowtile - X*3;
  const int h  = X >> 1;
  const int w0 = Yh * 16;
  const int l15 = lane & 15;
  const int qt  = lane >> 4;
  const int oc  = lane & 31;
  const int nh  = lane >> 5;

  const char* w2base = (const char*)w2p + (size_t)g*nch*65536;

  // ---- A fragments -> registers (16 coalesced b128 loads) ----
  bf16x8 a[2][8];
  {
    const bf16x8* ap = reinterpret_cast<const bf16x8*>(hmidp) + (size_t)rowtile*1024 + lane;
    #pragma unroll
    for (int mg = 0; mg < 2; ++mg)
      #pragma unroll
      for (int kb = 0; kb < 8; ++kb) a[mg][kb] = ap[(mg*8 + kb)*64];
  }

  // ---- bias table -> LDS (bf16, one-time) ----
  for (int i = tid; i < nch*128; i += 256)
    biasL[i] = (__bf16)b2[g*nch*128 + i];

  // ---- stage patches: pat[c][ki][wi][n]; thread = (n,c) ----
  {
    const int n = tid >> 5, c = tid & 31;
    const float* fsrc = F_LR + ((size_t)(n*CC + c)*HH)*WW;
    #pragma unroll
    for (int ki = 0; ki < 3; ++ki) {
      int hh = h - 1 + ki;
      bool hok = (unsigned)hh < (unsigned)HH;
      #pragma unroll
      for (int wi = 0; wi < 18; ++wi) {
        int ww = w0 - 1 + wi;
        float val = (hok && (unsigned)ww < (unsigned)WW) ? fsrc[hh*WW + ww] : 0.f;
        patB[((c*3 + ki)*18 + wi)*8 + n] = (__bf16)val;
      }
    }
  }
  BARRIER_LGKM();

  float oacc[8][4];
  #pragma unroll
  for (int i = 0; i < 8; ++i)
    { oacc[i][0]=0.f; oacc[i][1]=0.f; oacc[i][2]=0.f; oacc[i][3]=0.f; }

  // ---- B double buffer: two half-chunk register sets ----
  bf16x8 bA[2][4], bB[2][4];
  ISSUE_HALF(bA, 0, 0);
  ISSUE_HALF(bB, 0, 1);

  for (int ch = 0; ch < nch; ++ch) {
    f32x4 acc00 = {0,0,0,0}, acc01 = {0,0,0,0}, acc10 = {0,0,0,0}, acc11 = {0,0,0,0};

    // ---- consume half A (slices 0..3), then refill for ch+1 ----
    #pragma unroll
    for (int s = 0; s < 4; ++s) {
      acc00 = __builtin_amdgcn_mfma_f32_16x16x32_bf16(a[0][s], bA[0][s], acc00, 0,0,0);
      acc01 = __builtin_amdgcn_mfma_f32_16x16x32_bf16(a[0][s], bA[1][s], acc01, 0,0,0);
      acc10 = __builtin_amdgcn_mfma_f32_16x16x32_bf16(a[1][s], bA[0][s], acc10, 0,0,0);
      acc11 = __builtin_amdgcn_mfma_f32_16x16x32_bf16(a[1][s], bA[1][s], acc11, 0,0,0);
    }
    if (ch + 1 < nch) { ISSUE_HALF(bA, ch+1, 0); }

    // ---- consume half B (slices 4..7), then refill for ch+1 ----
    #pragma unroll
    for (int s = 0; s < 4; ++s) {
      acc00 = __builtin_amdgcn_mfma_f32_16x16x32_bf16(a[0][4+s], bB[0][s], acc00, 0,0,0);
      acc01 = __builtin_amdgcn_mfma_f32_16x16x32_bf16(a[0][4+s], bB[1][s], acc01, 0,0,0);
      acc10 = __builtin_amdgcn_mfma_f32_16x16x32_bf16(a[1][4+s], bB[0][s], acc10, 0,0,0);
      acc11 = __builtin_amdgcn_mfma_f32_16x16x32_bf16(a[1][4+s], bB[1][s], acc11, 0,0,0);
    }
    if (ch + 1 < nch) { ISSUE_HALF(bB, ch+1, 1); }

    // ---- wc write: wc[fl(=wv)][oc][r^swz] = acc + bias ----
    {
      float bias0 = (float)biasL[ch*128 + wv*32 + l15];
      float bias1 = (float)biasL[ch*128 + wv*32 + 16 + l15];
      #pragma unroll
      for (int mg = 0; mg < 2; ++mg) {
        #pragma unroll
        for (int ng = 0; ng < 2; ++ng) {
          f32x4 A = (mg==0) ? (ng==0?acc00:acc01) : (ng==0?acc10:acc11);
          float bb = ng ? bias1 : bias0;
          A[0]+=bb; A[1]+=bb; A[2]+=bb; A[3]+=bb;
          int ocx  = ng*16 + l15;
          int ridx = (mg*16 + qt*4) ^ ((ocx&7)<<2);
          *(f32x4*)&wc[wv*1024 + ocx*32 + ridx] = A;
        }
      }
    }
    BARRIER_LGKM();                        // wc visible (vmem stays in flight)

    // ---- apply ----
    const int swz = (oc & 7) << 2;
    #pragma unroll
    for (int fl = 0; fl < 4; ++fl) {
      const int f   = (g*nch + ch)*4 + fl;
      const int c   = f / 9;
      const int rem = f - c*9;
      const int ki  = rem / 3;
      const int kj  = rem - ki*3;
      const f32x4 wlo = *(const f32x4*)&wc[fl*1024 + oc*32 + ((wv*8    ) ^ swz)];
      const f32x4 whi = *(const f32x4*)&wc[fl*1024 + oc*32 + ((wv*8 + 4) ^ swz)];
      const __bf16* pbase = patB + (c*3 + ki)*18*8 + nh*4;
      #pragma unroll
      for (int rrh = 0; rrh < 4; ++rrh) {
        bf16x4 pq = *(const bf16x4*)(pbase + (wv*4 + rrh + kj)*8);
        float w0v = (rrh < 2) ? ((rrh == 0) ? wlo[0] : wlo[2]) : ((rrh == 2) ? whi[0] : whi[2]);
        float w1v = (rrh < 2) ? ((rrh == 0) ? wlo[1] : wlo[3]) : ((rrh == 2) ? whi[1] : whi[3]);
        #pragma unroll
        for (int q = 0; q < 4; ++q) {
          float pv = (float)pq[q];
          oacc[rrh*2][q]   += w0v * pv;
          oacc[rrh*2+1][q] += w1v * pv;
        }
      }
    }
    BARRIER_LGKM();                        // apply done; wc reusable
  }

  // ---- epilogue: out[n, oc, X, Yh*32 + wv*8 .. +7] ----
  float* OP = outp + (size_t)g*OUTSZ;
  #pragma unroll
  for (int q = 0; q < 4; ++q) {
    int n = nh*4 + q;
    f32x4 v0, v1;
    v0[0]=oacc[0][q]; v0[1]=oacc[1][q]; v0[2]=oacc[2][q]; v0[3]=oacc[3][q];
    v1[0]=oacc[4][q]; v1[1]=oacc[5][q]; v1[2]=oacc[6][q]; v1[3]=oacc[7][q];
    float* dst = OP + (((size_t)(n*OCC + oc)*XUP + X)*YUP + Yh*32 + wv*8);
    *(f32x4*)dst     = v0;
    *(f32x4*)(dst+4) = v1;
  }
}

// ---------------------------------------------------------------------------
// Kernel 4 (G=2 only): out = P0 + P1 (deterministic)
// ---------------------------------------------------------------------------
__global__ void reduce2(const float* __restrict__ P, float* __restrict__ out) {
  int i = blockIdx.x*256 + threadIdx.x;
  if (i < OUTSZ/4) {
    f32x4 a = ((const f32x4*)P)[i];
    f32x4 b = ((const f32x4*)(P + OUTSZ))[i];
    ((f32x4*)out)[i] = a + b;
  }
}

// ---------------------------------------------------------------------------
extern "C" void kernel_launch(void* const* d_in, const int* in_sizes, int n_in,
                              void* d_out, int out_size, void* d_ws, size_t ws_size,
                              hipStream_t stream) {
  const float* F_LR = (const float*)d_in[0];
  const float* v    = (const float*)d_in[1];
  const float* w1   = (const float*)d_in[2];
  const float* b1   = (const float*)d_in[3];
  const float* w2   = (const float*)d_in[4];
  const float* b2   = (const float*)d_in[5];
  float* out = (float*)d_out;

  const size_t prepBytes = (size_t)RTOT*HID*2;          // 4,718,592 each
  const size_t need2 = 2*prepBytes + 2ull*OUTSZ*4;      // 28,311,552
  const int G   = (ws_size >= need2) ? 2 : 1;
  const int nch = 72 / G;

  __hip_bfloat16* hmidp = (__hip_bfloat16*)d_ws;
  __hip_bfloat16* w2p   = (__hip_bfloat16*)((char*)d_ws + prepBytes);
  float* P = (float*)((char*)d_ws + 2*prepBytes);
  float* target = (G == 2) ? P : out;

  const size_t shmem = 27648 + 16384 + (size_t)nch*128*2;   // 53,248 (G=2)

  hipLaunchKernelGGL(prep_hmid, dim3(RTOT), dim3(HID), 0, stream, v, w1, b1, hmidp);
  hipLaunchKernelGGL(prep_w2,   dim3((HID*COLS)/256), dim3(256), 0, stream, w2, w2p);
  hipLaunchKernelGGL(fused_main, dim3(288*G), dim3(256), shmem, stream,
                     F_LR, hmidp, w2p, b2, target, G, nch);
  if (G == 2)
    hipLaunchKernelGGL(reduce2, dim3(OUTSZ/4/256), dim3(256), 0, stream, P, out);
}

// Round 12
// 174.680 us; speedup vs baseline: 1.2226x; 1.0084x over previous
//
#include <hip/hip_runtime.h>
#include <hip/hip_bf16.h>

// Problem constants
#define NN    8
#define CC    32
#define HH    48
#define WW    48
#define OCC   32
#define HID   256
#define FEAT  288          // C*K*K
#define RTOT  9216         // (H*S)*(W*S)
#define COLS  9216         // FEAT*OC
#define XUP   96
#define YUP   96
#define OUTSZ (NN*OCC*XUP*YUP)   // 2,359,296 floats

using bf16x8 = __attribute__((ext_vector_type(8))) __bf16;
using bf16x4 = __attribute__((ext_vector_type(4))) __bf16;
using f32x4  = __attribute__((ext_vector_type(4))) float;

#define GLOAD_LDS16(gp, lp)                                                        \
  __builtin_amdgcn_global_load_lds((const __attribute__((address_space(1))) void*)(gp), \
                                   (__attribute__((address_space(3))) void*)(lp), 16, 0, 0)

// ---------------------------------------------------------------------------
// Kernel 1: hmid = relu(v @ w1 + b1), bf16, MFMA A-fragment order (verified):
//   frag = (r/16)*8 + k/32 ; lane = ((k/8)%4)*16 + r%16 ; elem = k%8
// ---------------------------------------------------------------------------
__global__ void prep_hmid(const float* __restrict__ v, const float* __restrict__ w1,
                          const float* __restrict__ b1, __hip_bfloat16* __restrict__ hmidp) {
  int r = blockIdx.x;      // 0..9215
  int t = threadIdx.x;     // 0..255 = hidden index k
  float v0 = v[r*3+0], v1 = v[r*3+1], v2 = v[r*3+2];
  float val = v0*w1[t] + v1*w1[HID+t] + v2*w1[2*HID+t] + b1[t];
  val = fmaxf(val, 0.0f);
  int dst = ((r>>4)*8 + (t>>5))*512 + ((t>>3)&3)*128 + (r&15)*8 + (t&7);
  hmidp[dst] = __float2bfloat16(val);
}

// ---------------------------------------------------------------------------
// Kernel 2: w2 -> bf16, B-fragment order grouped into 8KB slices (verified):
//   colchunk = col/128 (72), kb = k/32 (8), cg = (col%128)/16 (8),
//   lane = ((k/8)%4)*16 + col%16, elem = k%8
// ---------------------------------------------------------------------------
__global__ void prep_w2(const float* __restrict__ w2, __hip_bfloat16* __restrict__ w2p) {
  int idx = blockIdx.x*256 + threadIdx.x;   // 0 .. 256*9216-1
  int k   = idx / COLS;
  int col = idx % COLS;
  float val = w2[idx];                      // w2[k][col], row-major
  int colchunk = col >> 7;
  int cg   = (col >> 4) & 7;
  int lane = (((k>>3)&3)<<4) | (col & 15);
  int kb   = k >> 5;
  int i    = k & 7;
  int dst  = (((colchunk*8 + kb)*8 + cg)*64 + lane)*8 + i;
  w2p[dst] = __float2bfloat16(val);
}

// ---------------------------------------------------------------------------
// Kernel 3: fused GEMM + apply.
// R12 CHANGE (one lever): A fragments move regs -> LDS (staged once, linear
// global_load_lds; re-read per chunk as conflict-free lane-major ds_read_b128).
// Frees 64 VGPRs so the bA/bB double-buffer can stay LIVE across the chunk
// (R11 post-mortem: VGPR=124 proves the compiler sank the prefetch).
// Everything else byte-identical to passing R11.
// LDS (dynamic): Atile 16384 + pat 27648 + wc 16384 + biasL = 65,024 (G=2).
// ---------------------------------------------------------------------------
#define BARRIER_LGKM() do {                              \
    asm volatile("s_waitcnt lgkmcnt(0)" ::: "memory");   \
    __builtin_amdgcn_sched_barrier(0);                   \
    __builtin_amdgcn_s_barrier();                        \
  } while (0)

#define ISSUE_HALF(SET, CH, H) do {                                              \
    const char* _b = w2base + ((size_t)((CH)*8 + (H)*4))*8192 + wv*2048          \
                     + (size_t)lane*16;                                          \
    _Pragma("unroll")                                                            \
    for (int _i = 0; _i < 4; ++_i) {                                             \
      SET[0][_i] = *(const bf16x8*)(_b + _i*8192);                               \
      SET[1][_i] = *(const bf16x8*)(_b + _i*8192 + 1024);                        \
    }                                                                            \
  } while (0)

__launch_bounds__(256, 2)
__global__ void fused_main(const float* __restrict__ F_LR,
                           const __hip_bfloat16* __restrict__ hmidp,
                           const __hip_bfloat16* __restrict__ w2p,
                           const float* __restrict__ b2,
                           float* __restrict__ outp,
                           int G, int nch) {
  extern __shared__ __align__(16) char smem[];
  char*   AtileB = smem;                         // 16384B: [mg*8+kb][lane][8] bf16
  __bf16* patB   = (__bf16*)(smem + 16384);      // 27648B: pat[c][ki][wi(18)][n(8)]
  float*  wc     = (float*)(smem + 44032);       // 16384B: [fl][oc][r^swz]
  __bf16* biasL  = (__bf16*)(smem + 60416);      // nch*128 bf16

  const int tid  = threadIdx.x;
  const int lane = tid & 63;
  const int wv   = tid >> 6;
  const int blk  = blockIdx.x;
  int rowtile, g;
  if (G == 2) {            // XCD-chunked decode (grid = 576, 72 blocks per XCD)
    int xcd = blk & 7;
    int j   = blk >> 3;    // 0..71
    g       = xcd & 1;
    rowtile = (xcd >> 1)*72 + j;
  } else {
    rowtile = blk;
    g       = 0;
  }
  const int X  = rowtile / 3;
  const int Yh = rowtile - X*3;
  const int h  = X >> 1;
  const int w0 = Yh * 16;
  const int l15 = lane & 15;
  const int qt  = lane >> 4;
  const int oc  = lane & 31;
  const int nh  = lane >> 5;

  const char* w2base = (const char*)w2p + (size_t)g*nch*65536;

  // ---- A tile -> LDS (16KB linear, R2-proven global_load_lds pattern) ----
  {
    const char* hsrc = (const char*)hmidp + (size_t)rowtile*16384;
    #pragma unroll
    for (int j = 0; j < 4; ++j)
      GLOAD_LDS16(hsrc + j*4096 + wv*1024 + lane*16, AtileB + j*4096 + wv*1024);
  }

  // ---- bias table -> LDS (bf16, one-time) ----
  for (int i = tid; i < nch*128; i += 256)
    biasL[i] = (__bf16)b2[g*nch*128 + i];

  // ---- stage patches: pat[c][ki][wi][n]; thread = (n,c) ----
  {
    const int n = tid >> 5, c = tid & 31;
    const float* fsrc = F_LR + ((size_t)(n*CC + c)*HH)*WW;
    #pragma unroll
    for (int ki = 0; ki < 3; ++ki) {
      int hh = h - 1 + ki;
      bool hok = (unsigned)hh < (unsigned)HH;
      #pragma unroll
      for (int wi = 0; wi < 18; ++wi) {
        int ww = w0 - 1 + wi;
        float val = (hok && (unsigned)ww < (unsigned)WW) ? fsrc[hh*WW + ww] : 0.f;
        patB[((c*3 + ki)*18 + wi)*8 + n] = (__bf16)val;
      }
    }
  }
  asm volatile("s_waitcnt vmcnt(0) lgkmcnt(0)" ::: "memory");
  __builtin_amdgcn_sched_barrier(0);
  __builtin_amdgcn_s_barrier();                  // Atile/pat/bias all visible

  float oacc[8][4];
  #pragma unroll
  for (int i = 0; i < 8; ++i)
    { oacc[i][0]=0.f; oacc[i][1]=0.f; oacc[i][2]=0.f; oacc[i][3]=0.f; }

  // ---- B double buffer: two half-chunk register sets (now FIT in VGPRs) ----
  bf16x8 bA[2][4], bB[2][4];
  ISSUE_HALF(bA, 0, 0);
  ISSUE_HALF(bB, 0, 1);

  for (int ch = 0; ch < nch; ++ch) {
    f32x4 acc00 = {0,0,0,0}, acc01 = {0,0,0,0}, acc10 = {0,0,0,0}, acc11 = {0,0,0,0};

    // ---- consume half A (slices 0..3; A frags from LDS), refill for ch+1 ----
    #pragma unroll
    for (int s = 0; s < 4; ++s) {
      bf16x8 a0 = *(const bf16x8*)(AtileB + s*1024 + lane*16);
      bf16x8 a1 = *(const bf16x8*)(AtileB + 8192 + s*1024 + lane*16);
      acc00 = __builtin_amdgcn_mfma_f32_16x16x32_bf16(a0, bA[0][s], acc00, 0,0,0);
      acc01 = __builtin_amdgcn_mfma_f32_16x16x32_bf16(a0, bA[1][s], acc01, 0,0,0);
      acc10 = __builtin_amdgcn_mfma_f32_16x16x32_bf16(a1, bA[0][s], acc10, 0,0,0);
      acc11 = __builtin_amdgcn_mfma_f32_16x16x32_bf16(a1, bA[1][s], acc11, 0,0,0);
    }
    if (ch + 1 < nch) { ISSUE_HALF(bA, ch+1, 0); }

    // ---- consume half B (slices 4..7), refill for ch+1 ----
    #pragma unroll
    for (int s = 0; s < 4; ++s) {
      bf16x8 a0 = *(const bf16x8*)(AtileB + (4+s)*1024 + lane*16);
      bf16x8 a1 = *(const bf16x8*)(AtileB + 8192 + (4+s)*1024 + lane*16);
      acc00 = __builtin_amdgcn_mfma_f32_16x16x32_bf16(a0, bB[0][s], acc00, 0,0,0);
      acc01 = __builtin_amdgcn_mfma_f32_16x16x32_bf16(a0, bB[1][s], acc01, 0,0,0);
      acc10 = __builtin_amdgcn_mfma_f32_16x16x32_bf16(a1, bB[0][s], acc10, 0,0,0);
      acc11 = __builtin_amdgcn_mfma_f32_16x16x32_bf16(a1, bB[1][s], acc11, 0,0,0);
    }
    if (ch + 1 < nch) { ISSUE_HALF(bB, ch+1, 1); }

    // ---- wc write: wc[fl(=wv)][oc][r^swz] = acc + bias ----
    {
      float bias0 = (float)biasL[ch*128 + wv*32 + l15];
      float bias1 = (float)biasL[ch*128 + wv*32 + 16 + l15];
      #pragma unroll
      for (int mg = 0; mg < 2; ++mg) {
        #pragma unroll
        for (int ng = 0; ng < 2; ++ng) {
          f32x4 A = (mg==0) ? (ng==0?acc00:acc01) : (ng==0?acc10:acc11);
          float bb = ng ? bias1 : bias0;
          A[0]+=bb; A[1]+=bb; A[2]+=bb; A[3]+=bb;
          int ocx  = ng*16 + l15;
          int ridx = (mg*16 + qt*4) ^ ((ocx&7)<<2);
          *(f32x4*)&wc[wv*1024 + ocx*32 + ridx] = A;
        }
      }
    }
    BARRIER_LGKM();                        // wc visible (vmem stays in flight)

    // ---- apply ----
    const int swz = (oc & 7) << 2;
    #pragma unroll
    for (int fl = 0; fl < 4; ++fl) {
      const int f   = (g*nch + ch)*4 + fl;
      const int c   = f / 9;
      const int rem = f - c*9;
      const int ki  = rem / 3;
      const int kj  = rem - ki*3;
      const f32x4 wlo = *(const f32x4*)&wc[fl*1024 + oc*32 + ((wv*8    ) ^ swz)];
      const f32x4 whi = *(const f32x4*)&wc[fl*1024 + oc*32 + ((wv*8 + 4) ^ swz)];
      const __bf16* pbase = patB + (c*3 + ki)*18*8 + nh*4;
      #pragma unroll
      for (int rrh = 0; rrh < 4; ++rrh) {
        bf16x4 pq = *(const bf16x4*)(pbase + (wv*4 + rrh + kj)*8);
        float w0v = (rrh < 2) ? ((rrh == 0) ? wlo[0] : wlo[2]) : ((rrh == 2) ? whi[0] : whi[2]);
        float w1v = (rrh < 2) ? ((rrh == 0) ? wlo[1] : wlo[3]) : ((rrh == 2) ? whi[1] : whi[3]);
        #pragma unroll
        for (int q = 0; q < 4; ++q) {
          float pv = (float)pq[q];
          oacc[rrh*2][q]   += w0v * pv;
          oacc[rrh*2+1][q] += w1v * pv;
        }
      }
    }
    BARRIER_LGKM();                        // apply done; wc reusable
  }

  // ---- epilogue: out[n, oc, X, Yh*32 + wv*8 .. +7] ----
  float* OP = outp + (size_t)g*OUTSZ;
  #pragma unroll
  for (int q = 0; q < 4; ++q) {
    int n = nh*4 + q;
    f32x4 v0, v1;
    v0[0]=oacc[0][q]; v0[1]=oacc[1][q]; v0[2]=oacc[2][q]; v0[3]=oacc[3][q];
    v1[0]=oacc[4][q]; v1[1]=oacc[5][q]; v1[2]=oacc[6][q]; v1[3]=oacc[7][q];
    float* dst = OP + (((size_t)(n*OCC + oc)*XUP + X)*YUP + Yh*32 + wv*8);
    *(f32x4*)dst     = v0;
    *(f32x4*)(dst+4) = v1;
  }
}

// ---------------------------------------------------------------------------
// Kernel 4 (G=2 only): out = P0 + P1 (deterministic)
// ---------------------------------------------------------------------------
__global__ void reduce2(const float* __restrict__ P, float* __restrict__ out) {
  int i = blockIdx.x*256 + threadIdx.x;
  if (i < OUTSZ/4) {
    f32x4 a = ((const f32x4*)P)[i];
    f32x4 b = ((const f32x4*)(P + OUTSZ))[i];
    ((f32x4*)out)[i] = a + b;
  }
}

// ---------------------------------------------------------------------------
extern "C" void kernel_launch(void* const* d_in, const int* in_sizes, int n_in,
                              void* d_out, int out_size, void* d_ws, size_t ws_size,
                              hipStream_t stream) {
  const float* F_LR = (const float*)d_in[0];
  const float* v    = (const float*)d_in[1];
  const float* w1   = (const float*)d_in[2];
  const float* b1   = (const float*)d_in[3];
  const float* w2   = (const float*)d_in[4];
  const float* b2   = (const float*)d_in[5];
  float* out = (float*)d_out;

  const size_t prepBytes = (size_t)RTOT*HID*2;          // 4,718,592 each
  const size_t need2 = 2*prepBytes + 2ull*OUTSZ*4;      // 28,311,552
  const int G   = (ws_size >= need2) ? 2 : 1;
  const int nch = 72 / G;

  __hip_bfloat16* hmidp = (__hip_bfloat16*)d_ws;
  __hip_bfloat16* w2p   = (__hip_bfloat16*)((char*)d_ws + prepBytes);
  float* P = (float*)((char*)d_ws + 2*prepBytes);
  float* target = (G == 2) ? P : out;

  const size_t shmem = 16384 + 27648 + 16384 + (size_t)nch*128*2;   // 65,024 (G=2)

  hipLaunchKernelGGL(prep_hmid, dim3(RTOT), dim3(HID), 0, stream, v, w1, b1, hmidp);
  hipLaunchKernelGGL(prep_w2,   dim3((HID*COLS)/256), dim3(256), 0, stream, w2, w2p);
  hipLaunchKernelGGL(fused_main, dim3(288*G), dim3(256), shmem, stream,
                     F_LR, hmidp, w2p, b2, target, G, nch);
  if (G == 2)
    hipLaunchKernelGGL(reduce2, dim3(OUTSZ/4/256), dim3(256), 0, stream, P, out);
}